// Round 5
// baseline (170.212 us; speedup 1.0000x reference)
//
#include <hip/hip_runtime.h>
#include <stdint.h>

// Problem constants (from reference setup_inputs)
#define BNUM  8192
#define LROWS 32
#define MLAB  32
#define CCLS  96
#define WPB   4              // waves per block
#define SPW   2              // samples per wave (one per 32-lane half)
#define SPB   (WPB*SPW)      // 8 samples per block
#define NBLK  (BNUM/SPB)     // 1024 blocks

// Design:
//  P0: hoisted gather stream — lane u prefetches x[r, lab_u] for r=0..31
//      into registers FIRST (independent of P1), so HBM/L2 latency overlaps
//      Phase A compute.
//  P1 (lane-per-row): lane u owns row u of its half's sample. Two
//      independent 48-elem streams (ILP x2), strict '>' ascending scan keeps
//      jnp first-occurrence argmax. Zero cross-lane ops. {lse,pred} -> LDS.
//  P3 (lane-per-column): ceTab[r][u] = (pred_r==lab_u ? +1:-1)*(lse_r - xg)
//      from registers + LDS only (no memory traffic).
//  Phase B: DP wavefront carrying (D|cnt<<8, ce) along the reference
//      backtrace-predecessor field (verified exact in rounds 2/4).
__global__ __launch_bounds__(256, 4) void editloss_main(
    const float* __restrict__ x, const int* __restrict__ y,
    float* __restrict__ partial_sum, float* __restrict__ partial_cnt)
{
    __shared__ float  ceTab[SPB][LROWS * MLAB];  // 32 KB
    __shared__ float2 lpS[SPB][LROWS];           // 2 KB: {lse, (float)pred}
    __shared__ float  psum[SPB];
    __shared__ float  pcnt[SPB];

    const int w    = threadIdx.x >> 6;
    const int lane = threadIdx.x & 63;
    const int g    = lane >> 5;          // which sample of the wave
    const int u    = lane & 31;          // slot within 32-lane half
    const int s    = w * SPW + g;        // sample slot in block [0,8)
    const int sb   = blockIdx.x * SPB + s;

    const float* xs    = x + (size_t)sb * (LROWS * CCLS);
    const int    lab_u = y[sb * MLAB + u];

    // ---------- P0: hoisted gather stream (overlaps P1 compute) ----------
    float gbuf[LROWS];
    {
        const float* gcol = xs + lab_u;
#pragma unroll
        for (int r = 0; r < LROWS; ++r) gbuf[r] = gcol[r * CCLS];
    }

    // ---------- P1: lane-per-row argmax + logsumexp, 2 ILP streams ----------
    {
        const float4* rowv = (const float4*)(xs + (size_t)u * CCLS);
        float mA = -1e30f, mB = -1e30f;
        int   iA = 0,      iB = 0;
        float sA = 0.f,    sB = 0.f;
#pragma unroll
        for (int k = 0; k < 12; ++k) {           // stream A: elems 0..47
            const float4 v = rowv[k];
            const int base = k * 4;
            if (v.x > mA) { mA = v.x; iA = base + 0; }
            if (v.y > mA) { mA = v.y; iA = base + 1; }
            if (v.z > mA) { mA = v.z; iA = base + 2; }
            if (v.w > mA) { mA = v.w; iA = base + 3; }
            sA += __expf(v.x) + __expf(v.y) + __expf(v.z) + __expf(v.w);
        }
#pragma unroll
        for (int k = 0; k < 12; ++k) {           // stream B: elems 48..95
            const float4 v = rowv[12 + k];
            const int base = 48 + k * 4;
            if (v.x > mB) { mB = v.x; iB = base + 0; }
            if (v.y > mB) { mB = v.y; iB = base + 1; }
            if (v.z > mB) { mB = v.z; iB = base + 2; }
            if (v.w > mB) { mB = v.w; iB = base + 3; }
            sB += __expf(v.x) + __expf(v.y) + __expf(v.z) + __expf(v.w);
        }
        // strict '>': stream A (lower indices) wins ties -> first occurrence
        const int   idx = (mB > mA) ? iB : iA;
        const float lse = __logf(sA + sB);
        lpS[s][u] = make_float2(lse, (float)idx);
    }
    // Same-wave LDS producer/consumer: DS pipe is in-order per wave.
    asm volatile("s_waitcnt lgkmcnt(0)" ::: "memory");

    // ---------- P3: ceTab build (registers + LDS only) ----------
#pragma unroll
    for (int r = 0; r < LROWS; ++r) {
        const float2 lp = lpS[s][r];
        const float  ce = lp.x - gbuf[r];        // strictly > 0
        ceTab[s][r * MLAB + u] = ((int)lp.y == lab_u) ? ce : -ce;
    }
    asm volatile("s_waitcnt lgkmcnt(0)" ::: "memory");

    // ---------- Phase B: fused DP wavefront (round-2/4 verified) ----------
    // lane u = column j = u+1 (column 0 analytic). Carried: D|cnt<<8, ce-sum.
    const int j = u + 1;
    int   prevW = 0;   float prevCE = 0.f;
    int   diagW = 0;   float diagCE = 0.f;
#pragma unroll 4
    for (int d = 1; d <= LROWS + MLAB; ++d) {
        const int   lWs  = __shfl_up(prevW, 1);    // (i, j-1)
        const float lCEs = __shfl_up(prevCE, 1);
        const int i = d - j;
        // column 0 analytic: D(i,0)=i, cnt=0, ce=0
        const int   lW  = (u == 0) ? max(i, 0)     : lWs;
        const float lCE = (u == 0) ? 0.f           : lCEs;
        const int   dW  = (u == 0) ? max(i - 1, 0) : diagW;
        const float dCE = (u == 0) ? 0.f           : diagCE;
        int curW; float curCE;
        if (i <= 0) {                       // top row: D=j; i<0 lanes inactive
            curW = j; curCE = 0.f;
        } else if (i > LROWS) {             // column finished: hold final value
            curW = prevW; curCE = prevCE;
        } else {
            const int uD = prevW & 255, uC = prevW >> 8;
            const int lD = lW & 255,    lC = lW >> 8;
            const int dD = dW & 255,    dC = dW >> 8;
            const float ct  = ceTab[s][(i - 1) * MLAB + u];
            const int   c   = (ct < 0.f) ? 1 : 0;
            const int nD = min(min(uD, lD) + 1, dD + c);
            // reference backtrace tie-break: diag > up > left
            const bool dg = (dD + c == nD);
            const bool up = !dg && (uD + 1 == nD);
            int nC; float nCE;
            if (dg)      { nC = dC + 1; nCE = dCE + fabsf(ct); }
            else if (up) { nC = uC;     nCE = prevCE;          }
            else         { nC = lC;     nCE = lCE;             }
            curW = nD | (nC << 8);
            curCE = nCE;
        }
        diagW = lWs; diagCE = lCEs;         // raw shfl result becomes next diag
        prevW = curW; prevCE = curCE;
    }

    // lane u==31 (j=32) holds cell (32,32) after d=64
    if (u == 31) {
        const int cnt = prevW >> 8;
        psum[s] = (cnt > 0) ? prevCE / (float)cnt : 0.f;
        pcnt[s] = (cnt > 0) ? 1.f : 0.f;
    }
    __syncthreads();
    if (threadIdx.x == 0) {
        float ss = 0.f, cc = 0.f;
#pragma unroll
        for (int k = 0; k < SPB; ++k) { ss += psum[k]; cc += pcnt[k]; }
        partial_sum[blockIdx.x] = ss;
        partial_cnt[blockIdx.x] = cc;
    }
}

__global__ __launch_bounds__(256) void editloss_finalize(
    const float* __restrict__ partial_sum, const float* __restrict__ partial_cnt,
    float* __restrict__ out, int nblocks)
{
    float s = 0.f, c = 0.f;
    for (int k = threadIdx.x; k < nblocks; k += 256) {
        s += partial_sum[k];
        c += partial_cnt[k];
    }
#pragma unroll
    for (int d = 32; d >= 1; d >>= 1) {
        s += __shfl_xor(s, d);
        c += __shfl_xor(c, d);
    }
    __shared__ float ss[4], cc[4];
    const int w = threadIdx.x >> 6, lane = threadIdx.x & 63;
    if (lane == 0) { ss[w] = s; cc[w] = c; }
    __syncthreads();
    if (threadIdx.x == 0) {
        const float S  = ss[0] + ss[1] + ss[2] + ss[3];
        const float C2 = cc[0] + cc[1] + cc[2] + cc[3];
        out[0] = (C2 > 0.f) ? (S / C2) : 0.f;
    }
}

extern "C" void kernel_launch(void* const* d_in, const int* in_sizes, int n_in,
                              void* d_out, int out_size, void* d_ws, size_t ws_size,
                              hipStream_t stream) {
    const float* x = (const float*)d_in[0];
    const int*   y = (const int*)d_in[1];
    // d_in[2]=num_chars, d_in[3]=num_labels: constants L/M in this problem.
    float* out = (float*)d_out;

    float* partial_sum = (float*)d_ws;           // NBLK floats
    float* partial_cnt = partial_sum + NBLK;     // NBLK floats

    editloss_main<<<NBLK, 256, 0, stream>>>(x, y, partial_sum, partial_cnt);
    editloss_finalize<<<1, 256, 0, stream>>>(partial_sum, partial_cnt, out, NBLK);
}